// Round 1
// baseline (5435.633 us; speedup 1.0000x reference)
//
#include <hip/hip_runtime.h>

#define NE 400000
#define NN 25000
#define BLK 128
#define LDS_STRIDE 65   // 64 + 1 pad: bank = (tid + j) % 32 -> 2-way aliasing = free

__device__ __forceinline__ float fast_silu(float x) {
    // x * sigmoid(x) = x / (1 + exp(-x)); v_exp + v_rcp, ~1ulp each, fine vs 1e-4 rel tol
    float e = __expf(-x);
    return x * __builtin_amdgcn_rcpf(1.0f + e);
}

__global__ __launch_bounds__(BLK) void edge_mp_kernel(
    const float* __restrict__ node_feats,   // (25000, 32, 4)
    const float* __restrict__ edge_attrs,   // (400000, 4)
    const float* __restrict__ edge_feats,   // (400000, 8)
    const int*   __restrict__ senders,      // (400000,)
    const int*   __restrict__ receivers,    // (400000,)
    const float* __restrict__ W0,           // (8, 64)
    const float* __restrict__ W1,           // (64, 64)
    const float* __restrict__ W2,           // (64, 64)
    const float* __restrict__ W3,           // (64, 128)
    float*       __restrict__ out)          // (25000, 32, 8)
{
    __shared__ float hbuf[BLK * LDS_STRIDE];
    const int tid = threadIdx.x;
    const int e   = blockIdx.x * BLK + tid;
    if (e >= NE) return;

    float* hl = &hbuf[tid * LDS_STRIDE];   // thread-private slice, no barriers needed

    // ---- load edge features (8 floats, coalesced float4 x2) ----
    float4 ef0 = ((const float4*)edge_feats)[e * 2 + 0];
    float4 ef1 = ((const float4*)edge_feats)[e * 2 + 1];
    float ef[8] = {ef0.x, ef0.y, ef0.z, ef0.w, ef1.x, ef1.y, ef1.z, ef1.w};

    float acc[64];

    // ---- layer 0: 8 -> 64, scale 1/sqrt(8), silu.  Weights uniform -> s_load ----
    #pragma unroll
    for (int i = 0; i < 64; ++i) acc[i] = 0.0f;
    #pragma unroll
    for (int j = 0; j < 8; ++j) {
        const float xj = ef[j];
        const float* wrow = W0 + j * 64;
        #pragma unroll
        for (int i = 0; i < 64; ++i) acc[i] = fmaf(xj, wrow[i], acc[i]);
    }
    {
        const float s0 = 0.35355339059327373f;  // 1/sqrt(8)
        #pragma unroll
        for (int i = 0; i < 64; ++i) hl[i] = fast_silu(acc[i] * s0);
    }

    // ---- layer 1: 64 -> 64, scale 1/8, silu. Dynamic j-loop: 1 ds_read per 64 fmac ----
    #pragma unroll
    for (int i = 0; i < 64; ++i) acc[i] = 0.0f;
    #pragma unroll 4
    for (int j = 0; j < 64; ++j) {
        const float xj = hl[j];                 // ds_read_b32, 2-way bank alias (free)
        const float* wrow = W1 + j * 64;        // uniform -> SGPR
        #pragma unroll
        for (int i = 0; i < 64; ++i) acc[i] = fmaf(xj, wrow[i], acc[i]);
    }
    #pragma unroll
    for (int i = 0; i < 64; ++i) hl[i] = fast_silu(acc[i] * 0.125f);

    // ---- layer 2: 64 -> 64, scale 1/8, silu. Output straight to registers ----
    #pragma unroll
    for (int i = 0; i < 64; ++i) acc[i] = 0.0f;
    #pragma unroll 4
    for (int j = 0; j < 64; ++j) {
        const float xj = hl[j];
        const float* wrow = W2 + j * 64;
        #pragma unroll
        for (int i = 0; i < 64; ++i) acc[i] = fmaf(xj, wrow[i], acc[i]);
    }
    float h2[64];
    #pragma unroll
    for (int i = 0; i < 64; ++i) h2[i] = fast_silu(acc[i] * 0.125f);

    // ---- edge metadata ----
    const int snd = senders[e];
    const int rcv = receivers[e];
    const float4 a4 = ((const float4*)edge_attrs)[e];
    const float a_s = a4.x;
    const float av0 = a4.y, av1 = a4.z, av2 = a4.w;

    const float4* nf4 = (const float4*)(node_feats + (size_t)snd * 128);
    float* outp = out + (size_t)rcv * 256;

    const float mixscale  = 0.125f * 0.25f;        // W3 fan-in scale * 1/sqrt(16)
    const float inv_sqrt3 = 0.5773502691896258f;

    // ---- layer 3 fused with message formation + scatter-add ----
    #pragma unroll 2
    for (int c = 0; c < 32; ++c) {
        float m0 = 0.0f, m1 = 0.0f, m2 = 0.0f, m3 = 0.0f;
        const float* wc = W3 + c * 4;               // uniform -> s_load_dwordx4 per j
        #pragma unroll
        for (int j = 0; j < 64; ++j) {
            const float hj = h2[j];
            m0 = fmaf(hj, wc[j * 128 + 0], m0);
            m1 = fmaf(hj, wc[j * 128 + 1], m1);
            m2 = fmaf(hj, wc[j * 128 + 2], m2);
            m3 = fmaf(hj, wc[j * 128 + 3], m3);
        }
        m0 *= mixscale; m1 *= mixscale; m2 *= mixscale; m3 *= mixscale;

        const float4 x4 = nf4[c];                   // gather, L2/LLC resident
        const float s  = x4.x;
        const float v0 = x4.y, v1 = x4.z, v2 = x4.w;

        float* op = outp + c * 8;
        atomicAdd(op + 0, s * a_s * m0);
        const float dotva = v0 * av0 + v1 * av1 + v2 * av2;
        atomicAdd(op + 1, dotva * inv_sqrt3 * m1);
        atomicAdd(op + 2, s * av0 * m2);
        atomicAdd(op + 3, s * av1 * m2);
        atomicAdd(op + 4, s * av2 * m2);
        atomicAdd(op + 5, v0 * a_s * m3);
        atomicAdd(op + 6, v1 * a_s * m3);
        atomicAdd(op + 7, v2 * a_s * m3);
    }
}

extern "C" void kernel_launch(void* const* d_in, const int* in_sizes, int n_in,
                              void* d_out, int out_size, void* d_ws, size_t ws_size,
                              hipStream_t stream) {
    const float* node_feats = (const float*)d_in[0];
    const float* edge_attrs = (const float*)d_in[1];
    const float* edge_feats = (const float*)d_in[2];
    const int*   senders    = (const int*)d_in[3];
    const int*   receivers  = (const int*)d_in[4];
    const float* W0 = (const float*)d_in[5];
    const float* W1 = (const float*)d_in[6];
    const float* W2 = (const float*)d_in[7];
    const float* W3 = (const float*)d_in[8];
    float* outp = (float*)d_out;

    // output is poisoned 0xAA before every call -> zero it (capturable async memset)
    hipMemsetAsync(d_out, 0, (size_t)out_size * sizeof(float), stream);

    dim3 grid((NE + BLK - 1) / BLK), block(BLK);
    hipLaunchKernelGGL(edge_mp_kernel, grid, block, 0, stream,
                       node_feats, edge_attrs, edge_feats, senders, receivers,
                       W0, W1, W2, W3, outp);
}

// Round 2
// 500.156 us; speedup vs baseline: 10.8679x; 10.8679x over previous
//
#include <hip/hip_runtime.h>
#include <hip/hip_fp16.h>

#define NE 400000
#define NN 25000
#define BLK 128
#define LDS_STRIDE 65   // 64 + 1 pad: 2-way bank aliasing = free (m136)
#define MAXDEG 64       // max in-degree of Binomial(400K, 1/25K) is ~38; 64 is safe

// ---------- ws layout ----------
// [0, 102400000)                  : mix16  (__half, NE*128)    = 102.4 MB
// [102400000, +6400000)           : slots  (int, NN*MAXDEG)    = 6.4 MB
// [108800000, +100000)            : cnt    (int, NN)           = 0.1 MB
#define WS_MIX_BYTES   102400000ull
#define WS_SLOTS_BYTES 6400000ull
#define WS_CNT_BYTES   100000ull
#define WS_NEED (WS_MIX_BYTES + WS_SLOTS_BYTES + WS_CNT_BYTES)

__device__ __forceinline__ float fast_silu(float x) {
    float e = __expf(-x);
    return x * __builtin_amdgcn_rcpf(1.0f + e);
}

// ---------------- phase 0: padded-CSR build (400K small atomics) ----------------
__global__ __launch_bounds__(256) void build_kernel(
    const int* __restrict__ receivers, int* __restrict__ cnt, int* __restrict__ slots)
{
    int e = blockIdx.x * 256 + threadIdx.x;
    if (e >= NE) return;
    int r = receivers[e];
    int s = atomicAdd(&cnt[r], 1);
    if (s < MAXDEG) slots[r * MAXDEG + s] = e;
}

// ---------------- phase 1: per-edge MLP -> mix[128] in fp16 ----------------
__global__ __launch_bounds__(BLK) void mlp_kernel(
    const float* __restrict__ edge_feats,   // (NE, 8)
    const float* __restrict__ W0,           // (8, 64)
    const float* __restrict__ W1,           // (64, 64)
    const float* __restrict__ W2,           // (64, 64)
    const float* __restrict__ W3,           // (64, 128)
    __half*      __restrict__ mix16)        // (NE, 128)
{
    __shared__ float hbuf[BLK * LDS_STRIDE];
    const int tid = threadIdx.x;
    const int e   = blockIdx.x * BLK + tid;
    if (e >= NE) return;

    float* hl = &hbuf[tid * LDS_STRIDE];    // thread-private LDS slice, no barriers

    float4 ef0 = ((const float4*)edge_feats)[e * 2 + 0];
    float4 ef1 = ((const float4*)edge_feats)[e * 2 + 1];
    float ef[8] = {ef0.x, ef0.y, ef0.z, ef0.w, ef1.x, ef1.y, ef1.z, ef1.w};

    float acc[64];

    // layer 0: 8 -> 64, /sqrt(8), silu
    #pragma unroll
    for (int i = 0; i < 64; ++i) acc[i] = 0.0f;
    #pragma unroll
    for (int j = 0; j < 8; ++j) {
        const float xj = ef[j];
        const float* wrow = W0 + j * 64;      // uniform -> s_load
        #pragma unroll
        for (int i = 0; i < 64; ++i) acc[i] = fmaf(xj, wrow[i], acc[i]);
    }
    {
        const float s0 = 0.35355339059327373f;
        #pragma unroll
        for (int i = 0; i < 64; ++i) hl[i] = fast_silu(acc[i] * s0);
    }

    // layer 1: 64 -> 64, /8, silu  (dynamic j: 1 ds_read per 64 fmac)
    #pragma unroll
    for (int i = 0; i < 64; ++i) acc[i] = 0.0f;
    #pragma unroll 4
    for (int j = 0; j < 64; ++j) {
        const float xj = hl[j];
        const float* wrow = W1 + j * 64;
        #pragma unroll
        for (int i = 0; i < 64; ++i) acc[i] = fmaf(xj, wrow[i], acc[i]);
    }
    #pragma unroll
    for (int i = 0; i < 64; ++i) hl[i] = fast_silu(acc[i] * 0.125f);

    // layer 2: 64 -> 64, /8, silu -> registers
    #pragma unroll
    for (int i = 0; i < 64; ++i) acc[i] = 0.0f;
    #pragma unroll 4
    for (int j = 0; j < 64; ++j) {
        const float xj = hl[j];
        const float* wrow = W2 + j * 64;
        #pragma unroll
        for (int i = 0; i < 64; ++i) acc[i] = fmaf(xj, wrow[i], acc[i]);
    }
    float h2[64];
    #pragma unroll
    for (int i = 0; i < 64; ++i) h2[i] = fast_silu(acc[i] * 0.125f);

    // layer 3: 64 -> 128, scaled, store fp16 mix
    const float mixscale = 0.125f * 0.25f;  // /sqrt(64) fan-in * 1/sqrt(16) neighbors
    __half2* mp = (__half2*)(mix16 + (size_t)e * 128);
    #pragma unroll 2
    for (int c = 0; c < 32; ++c) {
        float m0 = 0.0f, m1 = 0.0f, m2 = 0.0f, m3 = 0.0f;
        const float* wc = W3 + c * 4;         // uniform -> s_load_dwordx4 per j
        #pragma unroll
        for (int j = 0; j < 64; ++j) {
            const float hj = h2[j];
            m0 = fmaf(hj, wc[j * 128 + 0], m0);
            m1 = fmaf(hj, wc[j * 128 + 1], m1);
            m2 = fmaf(hj, wc[j * 128 + 2], m2);
            m3 = fmaf(hj, wc[j * 128 + 3], m3);
        }
        mp[c * 2 + 0] = __floats2half2_rn(m0 * mixscale, m1 * mixscale);
        mp[c * 2 + 1] = __floats2half2_rn(m2 * mixscale, m3 * mixscale);
    }
}

// ---------------- phase 2: per-node gather, zero atomics ----------------
__global__ __launch_bounds__(64) void gather_kernel(
    const float* __restrict__ node_feats,   // (NN, 32, 4)
    const float* __restrict__ edge_attrs,   // (NE, 4)
    const int*   __restrict__ senders,      // (NE,)
    const __half* __restrict__ mix16,       // (NE, 128)
    const int*   __restrict__ cnt,
    const int*   __restrict__ slots,
    float*       __restrict__ out)          // (NN, 32, 8)
{
    const int n    = blockIdx.x;
    const int lane = threadIdx.x;           // lane l owns out floats [4l, 4l+4)
    const int c    = lane >> 1;
    const int kh   = lane & 1;              // 0 -> k=0..3, 1 -> k=4..7
    const float inv_sqrt3 = 0.5773502691896258f;

    int d = cnt[n];
    if (d > MAXDEG) d = MAXDEG;
    const int* sl = slots + n * MAXDEG;

    float a0 = 0.f, a1 = 0.f, a2 = 0.f, a3 = 0.f;
    for (int i = 0; i < d; ++i) {
        const int eid = sl[i];              // wave-uniform
        const int snd = senders[eid];
        const float4 a4v = ((const float4*)edge_attrs)[eid];
        const __half2* mpp = (const __half2*)(mix16 + (size_t)eid * 128 + c * 4);
        const float2 mA = __half22float2(mpp[0]);
        const float2 mB = __half22float2(mpp[1]);
        const float m0 = mA.x, m1 = mA.y, m2 = mB.x, m3 = mB.y;
        const float4 x4 = ((const float4*)(node_feats + (size_t)snd * 128))[c];
        const float s  = x4.x, v0 = x4.y, v1 = x4.z, v2 = x4.w;
        const float as = a4v.x, av0 = a4v.y, av1 = a4v.z, av2 = a4v.w;

        if (kh == 0) {
            a0 = fmaf(s * as, m0, a0);
            const float dotva = v0 * av0 + v1 * av1 + v2 * av2;
            a1 = fmaf(dotva * inv_sqrt3, m1, a1);
            a2 = fmaf(s * av0, m2, a2);
            a3 = fmaf(s * av1, m2, a3);
        } else {
            a0 = fmaf(s * av2, m2, a0);
            a1 = fmaf(v0 * as, m3, a1);
            a2 = fmaf(v1 * as, m3, a2);
            a3 = fmaf(v2 * as, m3, a3);
        }
    }
    float4 r; r.x = a0; r.y = a1; r.z = a2; r.w = a3;
    ((float4*)(out + (size_t)n * 256))[lane] = r;   // coalesced, covers deg-0 nodes
}

// ---------------- fallback: Round-1 monolithic atomic kernel ----------------
__global__ __launch_bounds__(BLK) void edge_mp_kernel(
    const float* __restrict__ node_feats, const float* __restrict__ edge_attrs,
    const float* __restrict__ edge_feats, const int* __restrict__ senders,
    const int* __restrict__ receivers, const float* __restrict__ W0,
    const float* __restrict__ W1, const float* __restrict__ W2,
    const float* __restrict__ W3, float* __restrict__ out)
{
    __shared__ float hbuf[BLK * LDS_STRIDE];
    const int tid = threadIdx.x;
    const int e   = blockIdx.x * BLK + tid;
    if (e >= NE) return;
    float* hl = &hbuf[tid * LDS_STRIDE];

    float4 ef0 = ((const float4*)edge_feats)[e * 2 + 0];
    float4 ef1 = ((const float4*)edge_feats)[e * 2 + 1];
    float ef[8] = {ef0.x, ef0.y, ef0.z, ef0.w, ef1.x, ef1.y, ef1.z, ef1.w};
    float acc[64];
    #pragma unroll
    for (int i = 0; i < 64; ++i) acc[i] = 0.0f;
    #pragma unroll
    for (int j = 0; j < 8; ++j) {
        const float xj = ef[j];
        const float* wrow = W0 + j * 64;
        #pragma unroll
        for (int i = 0; i < 64; ++i) acc[i] = fmaf(xj, wrow[i], acc[i]);
    }
    {
        const float s0 = 0.35355339059327373f;
        #pragma unroll
        for (int i = 0; i < 64; ++i) hl[i] = fast_silu(acc[i] * s0);
    }
    #pragma unroll
    for (int i = 0; i < 64; ++i) acc[i] = 0.0f;
    #pragma unroll 4
    for (int j = 0; j < 64; ++j) {
        const float xj = hl[j];
        const float* wrow = W1 + j * 64;
        #pragma unroll
        for (int i = 0; i < 64; ++i) acc[i] = fmaf(xj, wrow[i], acc[i]);
    }
    #pragma unroll
    for (int i = 0; i < 64; ++i) hl[i] = fast_silu(acc[i] * 0.125f);
    #pragma unroll
    for (int i = 0; i < 64; ++i) acc[i] = 0.0f;
    #pragma unroll 4
    for (int j = 0; j < 64; ++j) {
        const float xj = hl[j];
        const float* wrow = W2 + j * 64;
        #pragma unroll
        for (int i = 0; i < 64; ++i) acc[i] = fmaf(xj, wrow[i], acc[i]);
    }
    float h2[64];
    #pragma unroll
    for (int i = 0; i < 64; ++i) h2[i] = fast_silu(acc[i] * 0.125f);

    const int snd = senders[e];
    const int rcv = receivers[e];
    const float4 a4 = ((const float4*)edge_attrs)[e];
    const float a_s = a4.x, av0 = a4.y, av1 = a4.z, av2 = a4.w;
    const float4* nf4 = (const float4*)(node_feats + (size_t)snd * 128);
    float* outp = out + (size_t)rcv * 256;
    const float mixscale = 0.125f * 0.25f;
    const float inv_sqrt3 = 0.5773502691896258f;

    #pragma unroll 2
    for (int c = 0; c < 32; ++c) {
        float m0 = 0.0f, m1 = 0.0f, m2 = 0.0f, m3 = 0.0f;
        const float* wc = W3 + c * 4;
        #pragma unroll
        for (int j = 0; j < 64; ++j) {
            const float hj = h2[j];
            m0 = fmaf(hj, wc[j * 128 + 0], m0);
            m1 = fmaf(hj, wc[j * 128 + 1], m1);
            m2 = fmaf(hj, wc[j * 128 + 2], m2);
            m3 = fmaf(hj, wc[j * 128 + 3], m3);
        }
        m0 *= mixscale; m1 *= mixscale; m2 *= mixscale; m3 *= mixscale;
        const float4 x4 = nf4[c];
        const float s = x4.x, v0 = x4.y, v1 = x4.z, v2 = x4.w;
        float* op = outp + c * 8;
        atomicAdd(op + 0, s * a_s * m0);
        const float dotva = v0 * av0 + v1 * av1 + v2 * av2;
        atomicAdd(op + 1, dotva * inv_sqrt3 * m1);
        atomicAdd(op + 2, s * av0 * m2);
        atomicAdd(op + 3, s * av1 * m2);
        atomicAdd(op + 4, s * av2 * m2);
        atomicAdd(op + 5, v0 * a_s * m3);
        atomicAdd(op + 6, v1 * a_s * m3);
        atomicAdd(op + 7, v2 * a_s * m3);
    }
}

extern "C" void kernel_launch(void* const* d_in, const int* in_sizes, int n_in,
                              void* d_out, int out_size, void* d_ws, size_t ws_size,
                              hipStream_t stream) {
    const float* node_feats = (const float*)d_in[0];
    const float* edge_attrs = (const float*)d_in[1];
    const float* edge_feats = (const float*)d_in[2];
    const int*   senders    = (const int*)d_in[3];
    const int*   receivers  = (const int*)d_in[4];
    const float* W0 = (const float*)d_in[5];
    const float* W1 = (const float*)d_in[6];
    const float* W2 = (const float*)d_in[7];
    const float* W3 = (const float*)d_in[8];
    float* outp = (float*)d_out;

    if (ws_size >= WS_NEED) {
        char* w = (char*)d_ws;
        __half* mix16 = (__half*)w;
        int* slots = (int*)(w + WS_MIX_BYTES);
        int* cnt   = (int*)(w + WS_MIX_BYTES + WS_SLOTS_BYTES);

        hipMemsetAsync(cnt, 0, NN * sizeof(int), stream);
        hipLaunchKernelGGL(build_kernel, dim3((NE + 255) / 256), dim3(256), 0, stream,
                           receivers, cnt, slots);
        hipLaunchKernelGGL(mlp_kernel, dim3(NE / BLK), dim3(BLK), 0, stream,
                           edge_feats, W0, W1, W2, W3, mix16);
        hipLaunchKernelGGL(gather_kernel, dim3(NN), dim3(64), 0, stream,
                           node_feats, edge_attrs, senders, mix16, cnt, slots, outp);
    } else {
        // fallback: monolithic atomic kernel (correct but slow)
        hipMemsetAsync(d_out, 0, (size_t)out_size * sizeof(float), stream);
        hipLaunchKernelGGL(edge_mp_kernel, dim3(NE / BLK), dim3(BLK), 0, stream,
                           node_feats, edge_attrs, edge_feats, senders, receivers,
                           W0, W1, W2, W3, outp);
    }
}

// Round 3
// 241.593 us; speedup vs baseline: 22.4991x; 2.0702x over previous
//
#include <hip/hip_runtime.h>
#include <hip/hip_fp16.h>

#define NE 400000
#define NN 25000
#define MAXDEG 56       // Poisson(16): P(deg>=56) ~1e-15; was 64, shrunk to make room for wbuf
#define LDS_STRIDE 65

typedef __attribute__((ext_vector_type(8))) _Float16 half8;
typedef __attribute__((ext_vector_type(4))) float f32x4;

// ---------- ws layout (total kept == round-2's 108,900,000 B, known to fit) ----------
// [0, 102,400,000)            : mix16  (_Float16, NE*128)  = 102.4 MB
// [102,400,000, +5,600,000)   : slots  (int, NN*56)        =   5.6 MB
// [108,000,000, +100,000)     : cnt    (int, NN)           =   0.1 MB
// [108,100,000, +36,864)      : wbuf   (_Float16, 18,432)  = fragment-ordered weights
#define WS_MIX_BYTES   102400000ull
#define WS_SLOTS_OFF   102400000ull
#define WS_CNT_OFF     108000000ull
#define WS_WBUF_OFF    108100000ull
#define WS_NEED        108900000ull

// wbuf frag bases (in f16 units): L0: 4 frags, L1: 8, L2: 8, L3: 16 (each frag = 512 f16)
#define WB_L0 0
#define WB_L1 2048
#define WB_L2 6144
#define WB_L3 10240

__device__ __forceinline__ float fast_silu(float x) {
    float e = __expf(-x);
    return x * __builtin_amdgcn_rcpf(1.0f + e);
}

// ---------------- phase -1: weights -> fragment-linear f16, scales folded ----------------
// frag value at lane l, elem j:  B[k][n] with n = l&15, k = kt*32 + (l>>4)*8 + j
__global__ __launch_bounds__(64) void prep_weights(
    const float* __restrict__ W0, const float* __restrict__ W1,
    const float* __restrict__ W2, const float* __restrict__ W3,
    _Float16* __restrict__ wbuf)
{
    const int f    = blockIdx.x;      // 0..35
    const int lane = threadIdx.x;     // 0..63
    const int n    = lane & 15;
    const int quad = lane >> 4;

    const float* W; int K, N, kt, nt, fl, base; float scale;
    if (f < 4)       { W = W0; K = 8;  N = 64;  fl = f;      kt = 0;       nt = fl;     scale = 0.35355339059327373f; base = WB_L0; }
    else if (f < 12) { W = W1; K = 64; N = 64;  fl = f - 4;  kt = fl >> 2; nt = fl & 3; scale = 0.125f;   base = WB_L1; }
    else if (f < 20) { W = W2; K = 64; N = 64;  fl = f - 12; kt = fl >> 2; nt = fl & 3; scale = 0.125f;   base = WB_L2; }
    else             { W = W3; K = 64; N = 128; fl = f - 20; kt = fl >> 3; nt = fl & 7; scale = 0.03125f; base = WB_L3; }
    // 0.03125 = 1/sqrt(64) fan-in * 1/sqrt(16) avg-neighbors, folded into W3

    _Float16 v[8];
    #pragma unroll
    for (int j = 0; j < 8; ++j) {
        const int k = kt * 32 + quad * 8 + j;
        const float val = (k < K) ? W[k * N + nt * 16 + n] * scale : 0.0f;
        v[j] = (_Float16)val;
    }
    *(half8*)(wbuf + base + fl * 512 + lane * 8) = *(const half8*)v;
}

// ---------------- phase 0: padded-CSR build ----------------
__global__ __launch_bounds__(256) void build_kernel(
    const int* __restrict__ receivers, int* __restrict__ cnt, int* __restrict__ slots)
{
    int e = blockIdx.x * 256 + threadIdx.x;
    if (e >= NE) return;
    int r = receivers[e];
    int s = atomicAdd(&cnt[r], 1);
    if (s < MAXDEG) slots[r * MAXDEG + s] = e;
}

// ---------------- phase 1: MFMA MLP, 16 edges per wave ----------------
// A-layout: A[m=lane&15][k=quad*8+j]; C/D: col=lane&15, row=quad*4+reg (m89/m120 verified)
#define HS 72   // LDS row stride (f16): 144 B = 16-B aligned for ds_read_b128
__global__ __launch_bounds__(256) void mlp_mfma_kernel(
    const float*    __restrict__ edge_feats,   // (NE, 8)
    const _Float16* __restrict__ wbuf,
    _Float16*       __restrict__ mix16)        // (NE, 128)
{
    __shared__ _Float16 H[4 * 16 * HS];        // per-wave-private 16x64 tile (padded)
    const int wave = threadIdx.x >> 6;
    const int lane = threadIdx.x & 63;
    const int col  = lane & 15;                // A: m (edge). B: n. C/D: col (feature)
    const int quad = lane >> 4;
    const int e0   = (blockIdx.x * 4 + wave) * 16;

    _Float16* Hw = &H[wave * 16 * HS];
    const half8* wb = (const half8*)wbuf;      // frag load: wb[fragbase*64... ] per lane
    const f32x4 zero4 = {0.f, 0.f, 0.f, 0.f};

    // ---- L0 A-frag: edges' 8 features in quad 0, rest zero (K padded 8->32) ----
    half8 a0 = {0, 0, 0, 0, 0, 0, 0, 0};
    if (quad == 0) {
        const float4* efp = (const float4*)(edge_feats + (size_t)(e0 + col) * 8);
        const float4 x = efp[0], y = efp[1];
        a0[0] = (_Float16)x.x; a0[1] = (_Float16)x.y; a0[2] = (_Float16)x.z; a0[3] = (_Float16)x.w;
        a0[4] = (_Float16)y.x; a0[5] = (_Float16)y.y; a0[6] = (_Float16)y.z; a0[7] = (_Float16)y.w;
    }

    // ---- L0: 8(->32) -> 64 ----
    {
        f32x4 acc[4];
        #pragma unroll
        for (int nt = 0; nt < 4; ++nt)
            acc[nt] = __builtin_amdgcn_mfma_f32_16x16x32_f16(a0, wb[(WB_L0 / 512 + nt) * 64 + lane], zero4, 0, 0, 0);
        #pragma unroll
        for (int nt = 0; nt < 4; ++nt)
            #pragma unroll
            for (int r = 0; r < 4; ++r)
                Hw[(quad * 4 + r) * HS + nt * 16 + col] = (_Float16)fast_silu(acc[nt][r]);
    }

    // ---- L1, L2: 64 -> 64 (scales folded into weights) ----
    #pragma unroll
    for (int layer = 0; layer < 2; ++layer) {
        const int wbase = (layer == 0 ? WB_L1 : WB_L2) / 512;
        // A-frags (DS in-order per wave: these reads complete before the writes below)
        const half8 alo = *(const half8*)&Hw[col * HS + 0  + quad * 8];
        const half8 ahi = *(const half8*)&Hw[col * HS + 32 + quad * 8];
        f32x4 acc[4];
        #pragma unroll
        for (int nt = 0; nt < 4; ++nt) {
            acc[nt] = __builtin_amdgcn_mfma_f32_16x16x32_f16(alo, wb[(wbase + 0 + nt) * 64 + lane], zero4, 0, 0, 0);
            acc[nt] = __builtin_amdgcn_mfma_f32_16x16x32_f16(ahi, wb[(wbase + 4 + nt) * 64 + lane], acc[nt], 0, 0, 0);
        }
        #pragma unroll
        for (int nt = 0; nt < 4; ++nt)
            #pragma unroll
            for (int r = 0; r < 4; ++r)
                Hw[(quad * 4 + r) * HS + nt * 16 + col] = (_Float16)fast_silu(acc[nt][r]);
    }

    // ---- L3: 64 -> 128, scale folded; store f16 mix (layout: mix16[e][c*4+irrep]) ----
    {
        const half8 alo = *(const half8*)&Hw[col * HS + 0  + quad * 8];
        const half8 ahi = *(const half8*)&Hw[col * HS + 32 + quad * 8];
        #pragma unroll
        for (int nt = 0; nt < 8; ++nt) {
            f32x4 acc = __builtin_amdgcn_mfma_f32_16x16x32_f16(alo, wb[(WB_L3 / 512 + 0 + nt) * 64 + lane], zero4, 0, 0, 0);
            acc = __builtin_amdgcn_mfma_f32_16x16x32_f16(ahi, wb[(WB_L3 / 512 + 8 + nt) * 64 + lane], acc, 0, 0, 0);
            #pragma unroll
            for (int r = 0; r < 4; ++r)
                mix16[(size_t)(e0 + quad * 4 + r) * 128 + nt * 16 + col] = (_Float16)acc[r];
        }
    }
}

// ---------------- phase 2: per-node gather, zero atomics ----------------
__global__ __launch_bounds__(64) void gather_kernel(
    const float* __restrict__ node_feats,   // (NN, 32, 4)
    const float* __restrict__ edge_attrs,   // (NE, 4)
    const int*   __restrict__ senders,      // (NE,)
    const __half* __restrict__ mix16,       // (NE, 128)
    const int*   __restrict__ cnt,
    const int*   __restrict__ slots,
    float*       __restrict__ out)          // (NN, 32, 8)
{
    const int n    = blockIdx.x;
    const int lane = threadIdx.x;           // lane l owns out floats [4l, 4l+4)
    const int c    = lane >> 1;
    const int kh   = lane & 1;
    const float inv_sqrt3 = 0.5773502691896258f;

    int d = cnt[n];
    if (d > MAXDEG) d = MAXDEG;
    const int* sl = slots + n * MAXDEG;

    float a0 = 0.f, a1 = 0.f, a2 = 0.f, a3 = 0.f;
    for (int i = 0; i < d; ++i) {
        const int eid = sl[i];              // wave-uniform
        const int snd = senders[eid];
        const float4 a4v = ((const float4*)edge_attrs)[eid];
        const __half2* mpp = (const __half2*)(mix16 + (size_t)eid * 128 + c * 4);
        const float2 mA = __half22float2(mpp[0]);
        const float2 mB = __half22float2(mpp[1]);
        const float m0 = mA.x, m1 = mA.y, m2 = mB.x, m3 = mB.y;
        const float4 x4 = ((const float4*)(node_feats + (size_t)snd * 128))[c];
        const float s  = x4.x, v0 = x4.y, v1 = x4.z, v2 = x4.w;
        const float as = a4v.x, av0 = a4v.y, av1 = a4v.z, av2 = a4v.w;

        if (kh == 0) {
            a0 = fmaf(s * as, m0, a0);
            const float dotva = v0 * av0 + v1 * av1 + v2 * av2;
            a1 = fmaf(dotva * inv_sqrt3, m1, a1);
            a2 = fmaf(s * av0, m2, a2);
            a3 = fmaf(s * av1, m2, a3);
        } else {
            a0 = fmaf(s * av2, m2, a0);
            a1 = fmaf(v0 * as, m3, a1);
            a2 = fmaf(v1 * as, m3, a2);
            a3 = fmaf(v2 * as, m3, a3);
        }
    }
    float4 r; r.x = a0; r.y = a1; r.z = a2; r.w = a3;
    ((float4*)(out + (size_t)n * 256))[lane] = r;   // coalesced, covers deg-0 nodes
}

// ---------------- fallback: monolithic atomic kernel (round-1, correct but slow) ----------------
__global__ __launch_bounds__(128) void edge_mp_kernel(
    const float* __restrict__ node_feats, const float* __restrict__ edge_attrs,
    const float* __restrict__ edge_feats, const int* __restrict__ senders,
    const int* __restrict__ receivers, const float* __restrict__ W0,
    const float* __restrict__ W1, const float* __restrict__ W2,
    const float* __restrict__ W3, float* __restrict__ out)
{
    __shared__ float hbuf[128 * LDS_STRIDE];
    const int tid = threadIdx.x;
    const int e   = blockIdx.x * 128 + tid;
    if (e >= NE) return;
    float* hl = &hbuf[tid * LDS_STRIDE];

    float4 ef0 = ((const float4*)edge_feats)[e * 2 + 0];
    float4 ef1 = ((const float4*)edge_feats)[e * 2 + 1];
    float ef[8] = {ef0.x, ef0.y, ef0.z, ef0.w, ef1.x, ef1.y, ef1.z, ef1.w};
    float acc[64];
    #pragma unroll
    for (int i = 0; i < 64; ++i) acc[i] = 0.0f;
    #pragma unroll
    for (int j = 0; j < 8; ++j) {
        const float xj = ef[j];
        const float* wrow = W0 + j * 64;
        #pragma unroll
        for (int i = 0; i < 64; ++i) acc[i] = fmaf(xj, wrow[i], acc[i]);
    }
    {
        const float s0 = 0.35355339059327373f;
        #pragma unroll
        for (int i = 0; i < 64; ++i) hl[i] = fast_silu(acc[i] * s0);
    }
    #pragma unroll
    for (int i = 0; i < 64; ++i) acc[i] = 0.0f;
    #pragma unroll 4
    for (int j = 0; j < 64; ++j) {
        const float xj = hl[j];
        const float* wrow = W1 + j * 64;
        #pragma unroll
        for (int i = 0; i < 64; ++i) acc[i] = fmaf(xj, wrow[i], acc[i]);
    }
    #pragma unroll
    for (int i = 0; i < 64; ++i) hl[i] = fast_silu(acc[i] * 0.125f);
    #pragma unroll
    for (int i = 0; i < 64; ++i) acc[i] = 0.0f;
    #pragma unroll 4
    for (int j = 0; j < 64; ++j) {
        const float xj = hl[j];
        const float* wrow = W2 + j * 64;
        #pragma unroll
        for (int i = 0; i < 64; ++i) acc[i] = fmaf(xj, wrow[i], acc[i]);
    }
    float h2[64];
    #pragma unroll
    for (int i = 0; i < 64; ++i) h2[i] = fast_silu(acc[i] * 0.125f);

    const int snd = senders[e];
    const int rcv = receivers[e];
    const float4 a4 = ((const float4*)edge_attrs)[e];
    const float a_s = a4.x, av0 = a4.y, av1 = a4.z, av2 = a4.w;
    const float4* nf4 = (const float4*)(node_feats + (size_t)snd * 128);
    float* outp = out + (size_t)rcv * 256;
    const float mixscale = 0.03125f;
    const float inv_sqrt3 = 0.5773502691896258f;

    #pragma unroll 2
    for (int c = 0; c < 32; ++c) {
        float m0 = 0.0f, m1 = 0.0f, m2 = 0.0f, m3 = 0.0f;
        const float* wc = W3 + c * 4;
        #pragma unroll
        for (int j = 0; j < 64; ++j) {
            const float hj = h2[j];
            m0 = fmaf(hj, wc[j * 128 + 0], m0);
            m1 = fmaf(hj, wc[j * 128 + 1], m1);
            m2 = fmaf(hj, wc[j * 128 + 2], m2);
            m3 = fmaf(hj, wc[j * 128 + 3], m3);
        }
        m0 *= mixscale; m1 *= mixscale; m2 *= mixscale; m3 *= mixscale;
        const float4 x4 = nf4[c];
        const float s = x4.x, v0 = x4.y, v1 = x4.z, v2 = x4.w;
        float* op = outp + c * 8;
        atomicAdd(op + 0, s * a_s * m0);
        const float dotva = v0 * av0 + v1 * av1 + v2 * av2;
        atomicAdd(op + 1, dotva * inv_sqrt3 * m1);
        atomicAdd(op + 2, s * av0 * m2);
        atomicAdd(op + 3, s * av1 * m2);
        atomicAdd(op + 4, s * av2 * m2);
        atomicAdd(op + 5, v0 * a_s * m3);
        atomicAdd(op + 6, v1 * a_s * m3);
        atomicAdd(op + 7, v2 * a_s * m3);
    }
}

extern "C" void kernel_launch(void* const* d_in, const int* in_sizes, int n_in,
                              void* d_out, int out_size, void* d_ws, size_t ws_size,
                              hipStream_t stream) {
    const float* node_feats = (const float*)d_in[0];
    const float* edge_attrs = (const float*)d_in[1];
    const float* edge_feats = (const float*)d_in[2];
    const int*   senders    = (const int*)d_in[3];
    const int*   receivers  = (const int*)d_in[4];
    const float* W0 = (const float*)d_in[5];
    const float* W1 = (const float*)d_in[6];
    const float* W2 = (const float*)d_in[7];
    const float* W3 = (const float*)d_in[8];
    float* outp = (float*)d_out;

    if (ws_size >= WS_NEED) {
        char* w = (char*)d_ws;
        _Float16* mix16 = (_Float16*)w;
        int* slots = (int*)(w + WS_SLOTS_OFF);
        int* cnt   = (int*)(w + WS_CNT_OFF);
        _Float16* wbuf = (_Float16*)(w + WS_WBUF_OFF);

        hipMemsetAsync(cnt, 0, NN * sizeof(int), stream);
        hipLaunchKernelGGL(prep_weights, dim3(36), dim3(64), 0, stream,
                           W0, W1, W2, W3, wbuf);
        hipLaunchKernelGGL(build_kernel, dim3((NE + 255) / 256), dim3(256), 0, stream,
                           receivers, cnt, slots);
        hipLaunchKernelGGL(mlp_mfma_kernel, dim3(NE / 64), dim3(256), 0, stream,
                           edge_feats, wbuf, mix16);
        hipLaunchKernelGGL(gather_kernel, dim3(NN), dim3(64), 0, stream,
                           node_feats, edge_attrs, senders, (const __half*)mix16, cnt, slots, outp);
    } else {
        hipMemsetAsync(d_out, 0, (size_t)out_size * sizeof(float), stream);
        hipLaunchKernelGGL(edge_mp_kernel, dim3((NE + 127) / 128), dim3(128), 0, stream,
                           node_feats, edge_attrs, edge_feats, senders, receivers,
                           W0, W1, W2, W3, outp);
    }
}